// Round 16
// baseline (159.224 us; speedup 1.0000x reference)
//
#include <hip/hip_runtime.h>
#include <hip/hip_bf16.h>
#include <cstdint>

typedef float f32x4 __attribute__((ext_vector_type(4)));
typedef __bf16 bf16x8 __attribute__((ext_vector_type(8)));
typedef uint32_t uint2v __attribute__((ext_vector_type(2)));

#define MFMA_K32(A, B, C) __builtin_amdgcn_mfma_f32_16x16x32_bf16((A), (B), (C), 0, 0, 0)

#if __has_builtin(__builtin_amdgcn_exp2f)
#define EXP2(x) __builtin_amdgcn_exp2f(x)
#else
#define EXP2(x) exp2f(x)
#endif

// round-to-nearest-even f32 -> bf16 bits
static __device__ __forceinline__ uint16_t f2b(float f) {
    uint32_t u = __float_as_uint(f);
    uint32_t r = (u + 0x7fffu + ((u >> 16) & 1u)) >> 16;
    return (uint16_t)r;
}

// pack two f32 -> bf16x2 dword (low = a, high = b), RNE.
// m240: no builtin on gfx950 -- MUST be inline asm, else a ~7-op SW fallback
// compiles and dominates the VALU budget (R8: flash 65->49.6 us from this).
static __device__ __forceinline__ uint32_t packbf(float a, float b) {
    uint32_t r;
    asm("v_cvt_pk_bf16_f32 %0, %1, %2" : "=v"(r) : "v"(a), "v"(b));
    return r;
}

// ---------------- kernel 0: prep = peadd-tile OR W-convert per block -----
__global__ __launch_bounds__(512) void prep(const float* __restrict__ x,
                                            const float* __restrict__ wq,
                                            const float* __restrict__ wk,
                                            const float* __restrict__ wv,
                                            const float* __restrict__ wo,
                                            uint16_t* __restrict__ dst,
                                            uint16_t* __restrict__ tok) {
    __shared__ uint16_t T[64][65];
    int tid = threadIdx.x, bid = blockIdx.x;
    if (bid < 512) {
        int nt = bid & 63, ct = (bid >> 6) & 3, bb = bid >> 8;
        int n0 = nt << 6, c0 = ct << 6;
        int nl = tid & 63, cq = tid >> 6;  // cq 0..7, 8 channels each
        int n = n0 + nl;
        float pf = (float)((c0 & 128) ? nt : nl);
        int cbase = c0 + cq * 8;
        int ibase = (cbase & 127) >> 1;
        float dt = __expf((float)(2 * ibase) * -0.07195578415606394f);
#pragma unroll
        for (int j = 0; j < 4; ++j) {
            float sv, cv;
            __sincosf(pf * dt, &sv, &cv);
            int cl = cq * 8 + 2 * j;
            int cc = cbase + 2 * j;
            T[cl][nl]     = f2b(x[((size_t)(bb * 256 + cc) << 12) + n] + sv);
            T[cl + 1][nl] = f2b(x[((size_t)(bb * 256 + cc + 1) << 12) + n] + cv);
            dt *= 0.8659643233600653f;  // exp(-2*0.07195578415606394)
        }
        __syncthreads();
#pragma unroll
        for (int p = 0; p < 8; ++p) {
            int tl = cq * 8 + p;
            tok[(((size_t)(bb << 12) | (n0 + tl)) << 8) + c0 + nl] = T[nl][tl];
        }
    } else {
        int idx = (bid - 512) * 512 + tid;  // 0..262143
        int which = idx >> 16, off = idx & 65535;
        const float* s = (which == 0) ? wq : (which == 1) ? wk : (which == 2) ? wv : wo;
        dst[idx] = f2b(s[off]);
    }
}

// ---------------- kernel 1: QKV projection, W LDS-staged ------------------
__global__ __launch_bounds__(256) void qkv_gemm(const uint16_t* __restrict__ tok,
                                                const uint16_t* __restrict__ Wall,
                                                const float* __restrict__ bq,
                                                const float* __restrict__ bk,
                                                const float* __restrict__ bv,
                                                uint16_t* __restrict__ qo,
                                                uint16_t* __restrict__ ko,
                                                uint16_t* __restrict__ vo) {
    __shared__ __align__(16) uint16_t WS[64][264];
    int tid = threadIdx.x, wv = tid >> 6, lane = tid & 63;
    int c16 = lane & 15, quad = lane >> 4;
    int M0 = blockIdx.x * 64 + wv * 16;
    int O0 = blockIdx.y * 64;
    const uint16_t* arow = tok + (size_t)(M0 + c16) * 256;
    bf16x8 af[8];
#pragma unroll
    for (int kk = 0; kk < 8; ++kk) af[kk] = *(const bf16x8*)(arow + kk * 32 + quad * 8);
    f32x4 zero = {0.f, 0.f, 0.f, 0.f};
    int bb = M0 >> 12, n = (M0 + c16) & 4095;
    int srow = tid >> 5, sch = (tid & 31) << 3;  // staging: 2048 elems/pass
    for (int mat = 0; mat < 3; ++mat) {
        const uint16_t* Wg = Wall + (size_t)mat * 65536 + (size_t)O0 * 256;
        __syncthreads();  // previous WS readers done
#pragma unroll
        for (int p = 0; p < 8; ++p)
            *(bf16x8*)(&WS[p * 8 + srow][sch]) = *(const bf16x8*)(Wg + (p * 8 + srow) * 256 + sch);
        __syncthreads();
        f32x4 acc[4] = {zero, zero, zero, zero};
#pragma unroll
        for (int kk = 0; kk < 8; ++kk) {
            int k0 = kk * 32 + quad * 8;
#pragma unroll
            for (int nb = 0; nb < 4; ++nb)
                acc[nb] = MFMA_K32(*(const bf16x8*)(&WS[nb * 16 + c16][k0]),
                                   af[kk], acc[nb]);  // D[o][n]
        }
        const float* bias = (mat == 0) ? bq : (mat == 1) ? bk : bv;
        if (mat < 2) {
            // q gets 1/sqrt(32)*log2(e) folded in (softmax uses exp2)
            float scale = (mat == 0) ? 0.25505654134660127f : 1.0f;
            uint16_t* dst = (mat == 0) ? qo : ko;
#pragma unroll
            for (int nb = 0; nb < 4; ++nb) {
                int o = O0 + nb * 16 + quad * 4;          // o..o+3, same head
                f32x4 bi = *(const f32x4*)(bias + o);
                int h = o >> 5, dd = o & 31;
                uint2v pk;
                pk[0] = packbf((acc[nb][0] + bi[0]) * scale, (acc[nb][1] + bi[1]) * scale);
                pk[1] = packbf((acc[nb][2] + bi[2]) * scale, (acc[nb][3] + bi[3]) * scale);
                *(uint2v*)(dst + ((size_t)(bb * 8 + h) * 4096 + n) * 32 + dd) = pk;
            }
        } else {
            // V^T [bh,d,n]
#pragma unroll
            for (int nb = 0; nb < 4; ++nb)
#pragma unroll
                for (int r = 0; r < 4; ++r) {
                    int o = O0 + nb * 16 + quad * 4 + r;
                    vo[((size_t)(bb * 8 + (o >> 5)) * 32 + (o & 31)) * 4096 + n] =
                        f2b(acc[nb][r] + bias[o]);
                }
        }
    }
}

// ---------------- kernel 2: flash attention, kv-split-4 ------------------
// R14 structure (proven 133.1us best): 64 q-rows/wave, 2 blocks/CU,
// kv-split-4, 16 iters, 4 staging buffers. R16 = R14 + s_setprio(1) around
// the compute cluster ONLY (T5). R15's "#pragma unroll 2" miscompiled
// (absmax 298) -- do NOT hand-unroll this barrier/double-buffer loop.
__global__ __launch_bounds__(512, 4) void flash(const uint16_t* __restrict__ qb,
                                                const uint16_t* __restrict__ kb,
                                                const uint16_t* __restrict__ vtb,
                                                uint16_t* __restrict__ concat) {
    // per kq group: KT[2][64][40] (10240 B) + VT[2][32][72] (9216 B) = 19456 B
    __shared__ __align__(16) char smem[77824];
    int tid = threadIdx.x, wv = tid >> 6, lane = tid & 63;
    int c16 = lane & 15, quad = lane >> 4;
    int kq = tid >> 7, t2 = tid & 127;   // staging group = kv quarter
    int bh = blockIdx.y;
    int qg = wv & 1;
    int q0 = (blockIdx.x << 7) + qg * 64;   // 64 q-rows per wave
    size_t base = (size_t)bh << 12;

    // staging pointers (2 slots each for K and V; 128 threads per group)
    uint16_t* KTg = (uint16_t*)(smem + kq * 19456);   // [2][64][40]
    uint16_t* VTg = KTg + 5120;                       // [2][32][72]
    const uint16_t* kgp = kb + (base + (size_t)kq * 1024 + (t2 >> 2)) * 32 + (t2 & 3) * 8;
    const uint16_t* vgp = vtb + ((size_t)bh * 32 + (t2 >> 3)) * 4096 + kq * 1024 + (t2 & 7) * 8;
    uint16_t* kls = KTg + (t2 >> 2) * 40 + (t2 & 3) * 8;   // + buf*2560; slot2 +1280
    uint16_t* vls = VTg + (t2 >> 3) * 72 + (t2 & 7) * 8;   // + buf*2304; slot2 +1152

    // fragment-read base for this wave's kv-quarter buffer
    uint16_t* KTw = (uint16_t*)(smem + (wv >> 1) * 19456);
    uint16_t* VTw = KTw + 5120;

    bf16x8 qf[4];
#pragma unroll
    for (int qbk = 0; qbk < 4; ++qbk)
        qf[qbk] = *(const bf16x8*)(qb + (base + q0 + qbk * 16 + c16) * 32 + quad * 8);

    // permuted K-row base for the QK A-operand
    int rbase = ((c16 >> 2) << 3) + (c16 & 3);

    union { uint32_t u[4]; bf16x8 v; } onesu;
    onesu.u[0] = 0x3F803F80u; onesu.u[1] = 0x3F803F80u;
    onesu.u[2] = 0x3F803F80u; onesu.u[3] = 0x3F803F80u;
    bf16x8 ones = onesu.v;

    f32x4 zero = {0.f, 0.f, 0.f, 0.f};
    f32x4 oA[4], oB[4], oS[4];
#pragma unroll
    for (int qbk = 0; qbk < 4; ++qbk) { oA[qbk] = zero; oB[qbk] = zero; oS[qbk] = zero; }

    // prologue: stage tile 0 into buf 0 (2 K slots + 2 V slots per thread)
    {
        bf16x8 k0 = *(const bf16x8*)kgp;
        bf16x8 k1 = *(const bf16x8*)(kgp + 1024);      // +32 rows
        bf16x8 v0 = *(const bf16x8*)vgp;
        bf16x8 v1 = *(const bf16x8*)(vgp + (size_t)16 * 4096);  // +16 d rows
        *(bf16x8*)kls = k0;
        *(bf16x8*)(kls + 1280) = k1;
        *(bf16x8*)vls = v0;
        *(bf16x8*)(vls + 1152) = v1;
    }
    __syncthreads();

    for (int kt = 0; kt < 16; ++kt) {
        int cur = kt & 1;
        int kn = (kt + 1) & 15;  // last iter re-loads tile 0 (in-bounds, unused)
        bf16x8 k0 = *(const bf16x8*)(kgp + (size_t)kn * 2048);
        bf16x8 k1 = *(const bf16x8*)(kgp + (size_t)kn * 2048 + 1024);
        bf16x8 v0 = *(const bf16x8*)(vgp + kn * 64);
        bf16x8 v1 = *(const bf16x8*)(vgp + (size_t)16 * 4096 + kn * 64);
        const uint16_t* kfp = KTw + cur * 2560 + rbase * 40 + quad * 8;
        const uint16_t* vfp = VTw + cur * 2304 + c16 * 72 + quad * 8;
        bf16x8 kf[4], vA[2], vB[2];
        kf[0] = *(const bf16x8*)(kfp);                 // p0 j0: rows rbase
        kf[1] = *(const bf16x8*)(kfp + 160);           // p0 j1: rows rbase+4
        kf[2] = *(const bf16x8*)(kfp + 1280);          // p1 j0: rows rbase+32
        kf[3] = *(const bf16x8*)(kfp + 1440);          // p1 j1: rows rbase+36
        vA[0] = *(const bf16x8*)(vfp);                 // d=c16,    seq quad*8
        vA[1] = *(const bf16x8*)(vfp + 32);            // d=c16,    seq 32+quad*8
        vB[0] = *(const bf16x8*)(vfp + 1152);          // d=16+c16, seq quad*8
        vB[1] = *(const bf16x8*)(vfp + 1152 + 32);     // d=16+c16, seq 32+quad*8

        __builtin_amdgcn_s_setprio(1);
#pragma unroll
        for (int qbk = 0; qbk < 4; ++qbk) {
            // QK^T: 4 independent MFMAs for this q-block
            f32x4 s[4];
#pragma unroll
            for (int c = 0; c < 4; ++c) s[c] = MFMA_K32(kf[c], qf[qbk], zero);
            // exp2 -> pack -> PV per p
#pragma unroll
            for (int p = 0; p < 2; ++p) {
#pragma unroll
                for (int r = 0; r < 4; ++r) {
                    s[2 * p][r] = EXP2(s[2 * p][r]);
                    s[2 * p + 1][r] = EXP2(s[2 * p + 1][r]);
                }
                union { bf16x8 v; uint32_t u[4]; } pa;
                pa.u[0] = packbf(s[2 * p][0], s[2 * p][1]);
                pa.u[1] = packbf(s[2 * p][2], s[2 * p][3]);
                pa.u[2] = packbf(s[2 * p + 1][0], s[2 * p + 1][1]);
                pa.u[3] = packbf(s[2 * p + 1][2], s[2 * p + 1][3]);
                oA[qbk] = MFMA_K32(pa.v, vA[p], oA[qbk]);
                oB[qbk] = MFMA_K32(pa.v, vB[p], oB[qbk]);
                oS[qbk] = MFMA_K32(pa.v, ones, oS[qbk]);
            }
        }
        __builtin_amdgcn_s_setprio(0);

        *(bf16x8*)(kls + (cur ^ 1) * 2560) = k0;
        *(bf16x8*)(kls + (cur ^ 1) * 2560 + 1280) = k1;
        *(bf16x8*)(vls + (cur ^ 1) * 2304) = v0;
        *(bf16x8*)(vls + (cur ^ 1) * 2304 + 1152) = v1;
        __syncthreads();
    }

    // 4-way kv combine via LDS, single pass (staging area dead now).
    // waves 2..7 write their 48 partials at stride 49 (6*64*49*4 = 75264 B);
    // waves 0,1 (kq=0) sum partners kq=1..3 for their qg and write out.
    float* ov = (float*)smem;
    if (wv >= 2) {
        float* d = ov + ((wv - 2) * 64 + lane) * 49;
#pragma unroll
        for (int qbk = 0; qbk < 4; ++qbk)
#pragma unroll
            for (int r = 0; r < 4; ++r) {
                d[qbk * 12 + r]     = oA[qbk][r];
                d[qbk * 12 + 4 + r] = oB[qbk][r];
                d[qbk * 12 + 8 + r] = oS[qbk][r];
            }
    }
    __syncthreads();
    if (wv < 2) {
#pragma unroll
        for (int j = 0; j < 3; ++j) {
            const float* s = ov + ((wv + 2 * j) * 64 + lane) * 49;
#pragma unroll
            for (int qbk = 0; qbk < 4; ++qbk)
#pragma unroll
                for (int r = 0; r < 4; ++r) {
                    oA[qbk][r] += s[qbk * 12 + r];
                    oB[qbk][r] += s[qbk * 12 + 4 + r];
                    oS[qbk][r] += s[qbk * 12 + 8 + r];
                }
        }
        int h = bh & 7, bb = bh >> 3;
#pragma unroll
        for (int qbk = 0; qbk < 4; ++qbk)
#pragma unroll
            for (int r = 0; r < 4; ++r) {
                float inv = 1.f / oS[qbk][r];   // l row-aligned with o rows
                int n = q0 + qbk * 16 + quad * 4 + r;
                size_t row = ((size_t)bb * 4096 + n) * 256 + h * 32;
                concat[row + c16]      = f2b(oA[qbk][r] * inv);
                concat[row + 16 + c16] = f2b(oB[qbk][r] * inv);
            }
    }
}

// ---------------- kernel 3: output projection, W LDS-staged --------------
__global__ __launch_bounds__(256) void proj_gemm(const uint16_t* __restrict__ concat,
                                                 const uint16_t* __restrict__ Wo,
                                                 const float* __restrict__ bo,
                                                 float* __restrict__ out) {
    __shared__ __align__(16) uint16_t WS[64][264];
    int tid = threadIdx.x, wv = tid >> 6, lane = tid & 63;
    int c16 = lane & 15, quad = lane >> 4;
    int M0 = blockIdx.x * 64 + wv * 16;
    int O0 = blockIdx.y * 64;
    int srow = tid >> 5, sch = (tid & 31) << 3;
    const uint16_t* Wg = Wo + (size_t)O0 * 256;
#pragma unroll
    for (int p = 0; p < 8; ++p)
        *(bf16x8*)(&WS[p * 8 + srow][sch]) = *(const bf16x8*)(Wg + (p * 8 + srow) * 256 + sch);
    const uint16_t* crow = concat + (size_t)(M0 + c16) * 256;
    bf16x8 af[8];
#pragma unroll
    for (int kk = 0; kk < 8; ++kk) af[kk] = *(const bf16x8*)(crow + kk * 32 + quad * 8);
    __syncthreads();
    f32x4 zero = {0.f, 0.f, 0.f, 0.f};
    f32x4 acc[4] = {zero, zero, zero, zero};
#pragma unroll
    for (int kk = 0; kk < 8; ++kk) {
        int k0 = kk * 32 + quad * 8;
#pragma unroll
        for (int nb = 0; nb < 4; ++nb)
            acc[nb] = MFMA_K32(*(const bf16x8*)(&WS[nb * 16 + c16][k0]),
                               af[kk], acc[nb]);  // D[o][token]
    }
    int bb = M0 >> 12, n = (M0 + c16) & 4095;
#pragma unroll
    for (int nb = 0; nb < 4; ++nb)
#pragma unroll
        for (int r = 0; r < 4; ++r) {
            int o = O0 + nb * 16 + quad * 4 + r;
            out[((size_t)(bb * 256 + o) << 12) + n] = acc[nb][r] + bo[o];
        }
}

extern "C" void kernel_launch(void* const* d_in, const int* in_sizes, int n_in,
                              void* d_out, int out_size, void* d_ws, size_t ws_size,
                              hipStream_t stream) {
    const float* x  = (const float*)d_in[0];
    const float* Wq = (const float*)d_in[1];
    const float* bq = (const float*)d_in[2];
    const float* Wk = (const float*)d_in[3];
    const float* bk = (const float*)d_in[4];
    const float* Wv = (const float*)d_in[5];
    const float* bv = (const float*)d_in[6];
    const float* Wo = (const float*)d_in[7];
    const float* bo = (const float*)d_in[8];
    float* out = (float*)d_out;

    uint16_t* ws   = (uint16_t*)d_ws;
    uint16_t* Wb   = ws;                  // 4*65536 bf16
    uint16_t* tok  = Wb + 4 * 65536;      // [b,N,c]
    uint16_t* q    = tok + 2097152;       // [bh,n,d]
    uint16_t* k    = q + 2097152;         // [bh,n,d]
    uint16_t* vt   = k + 2097152;         // [bh,d,n]
    uint16_t* cc   = vt + 2097152;        // [b,n,c]

    prep<<<1024, 512, 0, stream>>>(x, Wq, Wk, Wv, Wo, Wb, tok);
    qkv_gemm<<<dim3(128, 4), 256, 0, stream>>>(tok, Wb, bq, bk, bv, q, k, vt);
    flash<<<dim3(32, 16), 512, 0, stream>>>(q, k, vt, cc);
    proj_gemm<<<dim3(128, 4), 256, 0, stream>>>(cc, Wb + 3 * 65536, bo, out);
}

// Round 17
// 131.931 us; speedup vs baseline: 1.2069x; 1.2069x over previous
//
#include <hip/hip_runtime.h>
#include <hip/hip_bf16.h>
#include <cstdint>

typedef float f32x4 __attribute__((ext_vector_type(4)));
typedef __bf16 bf16x8 __attribute__((ext_vector_type(8)));
typedef uint32_t uint2v __attribute__((ext_vector_type(2)));

#define MFMA_K32(A, B, C) __builtin_amdgcn_mfma_f32_16x16x32_bf16((A), (B), (C), 0, 0, 0)

#if __has_builtin(__builtin_amdgcn_exp2f)
#define EXP2(x) __builtin_amdgcn_exp2f(x)
#else
#define EXP2(x) exp2f(x)
#endif

// round-to-nearest-even f32 -> bf16 bits
static __device__ __forceinline__ uint16_t f2b(float f) {
    uint32_t u = __float_as_uint(f);
    uint32_t r = (u + 0x7fffu + ((u >> 16) & 1u)) >> 16;
    return (uint16_t)r;
}

// pack two f32 -> bf16x2 dword (low = a, high = b), RNE.
// m240: no builtin on gfx950 -- MUST be inline asm, else a ~7-op SW fallback
// compiles and dominates the VALU budget (R8: flash 65->49.6 us from this).
static __device__ __forceinline__ uint32_t packbf(float a, float b) {
    uint32_t r;
    asm("v_cvt_pk_bf16_f32 %0, %1, %2" : "=v"(r) : "v"(a), "v"(b));
    return r;
}

// ---------------- kernel 0: prep = peadd-tile OR W-convert per block -----
__global__ __launch_bounds__(512) void prep(const float* __restrict__ x,
                                            const float* __restrict__ wq,
                                            const float* __restrict__ wk,
                                            const float* __restrict__ wv,
                                            const float* __restrict__ wo,
                                            uint16_t* __restrict__ dst,
                                            uint16_t* __restrict__ tok) {
    __shared__ uint16_t T[64][65];
    int tid = threadIdx.x, bid = blockIdx.x;
    if (bid < 512) {
        int nt = bid & 63, ct = (bid >> 6) & 3, bb = bid >> 8;
        int n0 = nt << 6, c0 = ct << 6;
        int nl = tid & 63, cq = tid >> 6;  // cq 0..7, 8 channels each
        int n = n0 + nl;
        float pf = (float)((c0 & 128) ? nt : nl);
        int cbase = c0 + cq * 8;
        int ibase = (cbase & 127) >> 1;
        float dt = __expf((float)(2 * ibase) * -0.07195578415606394f);
#pragma unroll
        for (int j = 0; j < 4; ++j) {
            float sv, cv;
            __sincosf(pf * dt, &sv, &cv);
            int cl = cq * 8 + 2 * j;
            int cc = cbase + 2 * j;
            T[cl][nl]     = f2b(x[((size_t)(bb * 256 + cc) << 12) + n] + sv);
            T[cl + 1][nl] = f2b(x[((size_t)(bb * 256 + cc + 1) << 12) + n] + cv);
            dt *= 0.8659643233600653f;  // exp(-2*0.07195578415606394)
        }
        __syncthreads();
#pragma unroll
        for (int p = 0; p < 8; ++p) {
            int tl = cq * 8 + p;
            tok[(((size_t)(bb << 12) | (n0 + tl)) << 8) + c0 + nl] = T[nl][tl];
        }
    } else {
        int idx = (bid - 512) * 512 + tid;  // 0..262143
        int which = idx >> 16, off = idx & 65535;
        const float* s = (which == 0) ? wq : (which == 1) ? wk : (which == 2) ? wv : wo;
        dst[idx] = f2b(s[off]);
    }
}

// ---------------- kernel 1: QKV projection, W LDS-staged ------------------
__global__ __launch_bounds__(256) void qkv_gemm(const uint16_t* __restrict__ tok,
                                                const uint16_t* __restrict__ Wall,
                                                const float* __restrict__ bq,
                                                const float* __restrict__ bk,
                                                const float* __restrict__ bv,
                                                uint16_t* __restrict__ qo,
                                                uint16_t* __restrict__ ko,
                                                uint16_t* __restrict__ vo) {
    __shared__ __align__(16) uint16_t WS[64][264];
    int tid = threadIdx.x, wv = tid >> 6, lane = tid & 63;
    int c16 = lane & 15, quad = lane >> 4;
    int M0 = blockIdx.x * 64 + wv * 16;
    int O0 = blockIdx.y * 64;
    const uint16_t* arow = tok + (size_t)(M0 + c16) * 256;
    bf16x8 af[8];
#pragma unroll
    for (int kk = 0; kk < 8; ++kk) af[kk] = *(const bf16x8*)(arow + kk * 32 + quad * 8);
    f32x4 zero = {0.f, 0.f, 0.f, 0.f};
    int bb = M0 >> 12, n = (M0 + c16) & 4095;
    int srow = tid >> 5, sch = (tid & 31) << 3;  // staging: 2048 elems/pass
    for (int mat = 0; mat < 3; ++mat) {
        const uint16_t* Wg = Wall + (size_t)mat * 65536 + (size_t)O0 * 256;
        __syncthreads();  // previous WS readers done
#pragma unroll
        for (int p = 0; p < 8; ++p)
            *(bf16x8*)(&WS[p * 8 + srow][sch]) = *(const bf16x8*)(Wg + (p * 8 + srow) * 256 + sch);
        __syncthreads();
        f32x4 acc[4] = {zero, zero, zero, zero};
#pragma unroll
        for (int kk = 0; kk < 8; ++kk) {
            int k0 = kk * 32 + quad * 8;
#pragma unroll
            for (int nb = 0; nb < 4; ++nb)
                acc[nb] = MFMA_K32(*(const bf16x8*)(&WS[nb * 16 + c16][k0]),
                                   af[kk], acc[nb]);  // D[o][n]
        }
        const float* bias = (mat == 0) ? bq : (mat == 1) ? bk : bv;
        if (mat < 2) {
            // q gets 1/sqrt(32)*log2(e) folded in (softmax uses exp2)
            float scale = (mat == 0) ? 0.25505654134660127f : 1.0f;
            uint16_t* dst = (mat == 0) ? qo : ko;
#pragma unroll
            for (int nb = 0; nb < 4; ++nb) {
                int o = O0 + nb * 16 + quad * 4;          // o..o+3, same head
                f32x4 bi = *(const f32x4*)(bias + o);
                int h = o >> 5, dd = o & 31;
                uint2v pk;
                pk[0] = packbf((acc[nb][0] + bi[0]) * scale, (acc[nb][1] + bi[1]) * scale);
                pk[1] = packbf((acc[nb][2] + bi[2]) * scale, (acc[nb][3] + bi[3]) * scale);
                *(uint2v*)(dst + ((size_t)(bb * 8 + h) * 4096 + n) * 32 + dd) = pk;
            }
        } else {
            // V^T [bh,d,n]
#pragma unroll
            for (int nb = 0; nb < 4; ++nb)
#pragma unroll
                for (int r = 0; r < 4; ++r) {
                    int o = O0 + nb * 16 + quad * 4 + r;
                    vo[((size_t)(bb * 8 + (o >> 5)) * 32 + (o & 31)) * 4096 + n] =
                        f2b(acc[nb][r] + bias[o]);
                }
        }
    }
}

// ---------------- kernel 2: flash attention, kv-split-4 ------------------
// R14 structure (proven 133.1us session best): 64 q-rows/wave, 2 blocks/CU,
// kv-split-4, 16 iters, 4 staging buffers. R15 (unroll 2) miscompiled;
// R16 (setprio) caused cross-block priority inversion (flash 48.5->79us).
// This is the byte-exact R14 revert.
__global__ __launch_bounds__(512, 4) void flash(const uint16_t* __restrict__ qb,
                                                const uint16_t* __restrict__ kb,
                                                const uint16_t* __restrict__ vtb,
                                                uint16_t* __restrict__ concat) {
    // per kq group: KT[2][64][40] (10240 B) + VT[2][32][72] (9216 B) = 19456 B
    __shared__ __align__(16) char smem[77824];
    int tid = threadIdx.x, wv = tid >> 6, lane = tid & 63;
    int c16 = lane & 15, quad = lane >> 4;
    int kq = tid >> 7, t2 = tid & 127;   // staging group = kv quarter
    int bh = blockIdx.y;
    int qg = wv & 1;
    int q0 = (blockIdx.x << 7) + qg * 64;   // 64 q-rows per wave
    size_t base = (size_t)bh << 12;

    // staging pointers (2 slots each for K and V; 128 threads per group)
    uint16_t* KTg = (uint16_t*)(smem + kq * 19456);   // [2][64][40]
    uint16_t* VTg = KTg + 5120;                       // [2][32][72]
    const uint16_t* kgp = kb + (base + (size_t)kq * 1024 + (t2 >> 2)) * 32 + (t2 & 3) * 8;
    const uint16_t* vgp = vtb + ((size_t)bh * 32 + (t2 >> 3)) * 4096 + kq * 1024 + (t2 & 7) * 8;
    uint16_t* kls = KTg + (t2 >> 2) * 40 + (t2 & 3) * 8;   // + buf*2560; slot2 +1280
    uint16_t* vls = VTg + (t2 >> 3) * 72 + (t2 & 7) * 8;   // + buf*2304; slot2 +1152

    // fragment-read base for this wave's kv-quarter buffer
    uint16_t* KTw = (uint16_t*)(smem + (wv >> 1) * 19456);
    uint16_t* VTw = KTw + 5120;

    bf16x8 qf[4];
#pragma unroll
    for (int qbk = 0; qbk < 4; ++qbk)
        qf[qbk] = *(const bf16x8*)(qb + (base + q0 + qbk * 16 + c16) * 32 + quad * 8);

    // permuted K-row base for the QK A-operand
    int rbase = ((c16 >> 2) << 3) + (c16 & 3);

    union { uint32_t u[4]; bf16x8 v; } onesu;
    onesu.u[0] = 0x3F803F80u; onesu.u[1] = 0x3F803F80u;
    onesu.u[2] = 0x3F803F80u; onesu.u[3] = 0x3F803F80u;
    bf16x8 ones = onesu.v;

    f32x4 zero = {0.f, 0.f, 0.f, 0.f};
    f32x4 oA[4], oB[4], oS[4];
#pragma unroll
    for (int qbk = 0; qbk < 4; ++qbk) { oA[qbk] = zero; oB[qbk] = zero; oS[qbk] = zero; }

    // prologue: stage tile 0 into buf 0 (2 K slots + 2 V slots per thread)
    {
        bf16x8 k0 = *(const bf16x8*)kgp;
        bf16x8 k1 = *(const bf16x8*)(kgp + 1024);      // +32 rows
        bf16x8 v0 = *(const bf16x8*)vgp;
        bf16x8 v1 = *(const bf16x8*)(vgp + (size_t)16 * 4096);  // +16 d rows
        *(bf16x8*)kls = k0;
        *(bf16x8*)(kls + 1280) = k1;
        *(bf16x8*)vls = v0;
        *(bf16x8*)(vls + 1152) = v1;
    }
    __syncthreads();

    for (int kt = 0; kt < 16; ++kt) {
        int cur = kt & 1;
        int kn = (kt + 1) & 15;  // last iter re-loads tile 0 (in-bounds, unused)
        bf16x8 k0 = *(const bf16x8*)(kgp + (size_t)kn * 2048);
        bf16x8 k1 = *(const bf16x8*)(kgp + (size_t)kn * 2048 + 1024);
        bf16x8 v0 = *(const bf16x8*)(vgp + kn * 64);
        bf16x8 v1 = *(const bf16x8*)(vgp + (size_t)16 * 4096 + kn * 64);
        const uint16_t* kfp = KTw + cur * 2560 + rbase * 40 + quad * 8;
        const uint16_t* vfp = VTw + cur * 2304 + c16 * 72 + quad * 8;
        bf16x8 kf[4], vA[2], vB[2];
        kf[0] = *(const bf16x8*)(kfp);                 // p0 j0: rows rbase
        kf[1] = *(const bf16x8*)(kfp + 160);           // p0 j1: rows rbase+4
        kf[2] = *(const bf16x8*)(kfp + 1280);          // p1 j0: rows rbase+32
        kf[3] = *(const bf16x8*)(kfp + 1440);          // p1 j1: rows rbase+36
        vA[0] = *(const bf16x8*)(vfp);                 // d=c16,    seq quad*8
        vA[1] = *(const bf16x8*)(vfp + 32);            // d=c16,    seq 32+quad*8
        vB[0] = *(const bf16x8*)(vfp + 1152);          // d=16+c16, seq quad*8
        vB[1] = *(const bf16x8*)(vfp + 1152 + 32);     // d=16+c16, seq 32+quad*8

#pragma unroll
        for (int qbk = 0; qbk < 4; ++qbk) {
            // QK^T: 4 independent MFMAs for this q-block
            f32x4 s[4];
#pragma unroll
            for (int c = 0; c < 4; ++c) s[c] = MFMA_K32(kf[c], qf[qbk], zero);
            // exp2 -> pack -> PV per p
#pragma unroll
            for (int p = 0; p < 2; ++p) {
#pragma unroll
                for (int r = 0; r < 4; ++r) {
                    s[2 * p][r] = EXP2(s[2 * p][r]);
                    s[2 * p + 1][r] = EXP2(s[2 * p + 1][r]);
                }
                union { bf16x8 v; uint32_t u[4]; } pa;
                pa.u[0] = packbf(s[2 * p][0], s[2 * p][1]);
                pa.u[1] = packbf(s[2 * p][2], s[2 * p][3]);
                pa.u[2] = packbf(s[2 * p + 1][0], s[2 * p + 1][1]);
                pa.u[3] = packbf(s[2 * p + 1][2], s[2 * p + 1][3]);
                oA[qbk] = MFMA_K32(pa.v, vA[p], oA[qbk]);
                oB[qbk] = MFMA_K32(pa.v, vB[p], oB[qbk]);
                oS[qbk] = MFMA_K32(pa.v, ones, oS[qbk]);
            }
        }

        *(bf16x8*)(kls + (cur ^ 1) * 2560) = k0;
        *(bf16x8*)(kls + (cur ^ 1) * 2560 + 1280) = k1;
        *(bf16x8*)(vls + (cur ^ 1) * 2304) = v0;
        *(bf16x8*)(vls + (cur ^ 1) * 2304 + 1152) = v1;
        __syncthreads();
    }

    // 4-way kv combine via LDS, single pass (staging area dead now).
    // waves 2..7 write their 48 partials at stride 49 (6*64*49*4 = 75264 B);
    // waves 0,1 (kq=0) sum partners kq=1..3 for their qg and write out.
    float* ov = (float*)smem;
    if (wv >= 2) {
        float* d = ov + ((wv - 2) * 64 + lane) * 49;
#pragma unroll
        for (int qbk = 0; qbk < 4; ++qbk)
#pragma unroll
            for (int r = 0; r < 4; ++r) {
                d[qbk * 12 + r]     = oA[qbk][r];
                d[qbk * 12 + 4 + r] = oB[qbk][r];
                d[qbk * 12 + 8 + r] = oS[qbk][r];
            }
    }
    __syncthreads();
    if (wv < 2) {
#pragma unroll
        for (int j = 0; j < 3; ++j) {
            const float* s = ov + ((wv + 2 * j) * 64 + lane) * 49;
#pragma unroll
            for (int qbk = 0; qbk < 4; ++qbk)
#pragma unroll
                for (int r = 0; r < 4; ++r) {
                    oA[qbk][r] += s[qbk * 12 + r];
                    oB[qbk][r] += s[qbk * 12 + 4 + r];
                    oS[qbk][r] += s[qbk * 12 + 8 + r];
                }
        }
        int h = bh & 7, bb = bh >> 3;
#pragma unroll
        for (int qbk = 0; qbk < 4; ++qbk)
#pragma unroll
            for (int r = 0; r < 4; ++r) {
                float inv = 1.f / oS[qbk][r];   // l row-aligned with o rows
                int n = q0 + qbk * 16 + quad * 4 + r;
                size_t row = ((size_t)bb * 4096 + n) * 256 + h * 32;
                concat[row + c16]      = f2b(oA[qbk][r] * inv);
                concat[row + 16 + c16] = f2b(oB[qbk][r] * inv);
            }
    }
}

// ---------------- kernel 3: output projection, W LDS-staged --------------
__global__ __launch_bounds__(256) void proj_gemm(const uint16_t* __restrict__ concat,
                                                 const uint16_t* __restrict__ Wo,
                                                 const float* __restrict__ bo,
                                                 float* __restrict__ out) {
    __shared__ __align__(16) uint16_t WS[64][264];
    int tid = threadIdx.x, wv = tid >> 6, lane = tid & 63;
    int c16 = lane & 15, quad = lane >> 4;
    int M0 = blockIdx.x * 64 + wv * 16;
    int O0 = blockIdx.y * 64;
    int srow = tid >> 5, sch = (tid & 31) << 3;
    const uint16_t* Wg = Wo + (size_t)O0 * 256;
#pragma unroll
    for (int p = 0; p < 8; ++p)
        *(bf16x8*)(&WS[p * 8 + srow][sch]) = *(const bf16x8*)(Wg + (p * 8 + srow) * 256 + sch);
    const uint16_t* crow = concat + (size_t)(M0 + c16) * 256;
    bf16x8 af[8];
#pragma unroll
    for (int kk = 0; kk < 8; ++kk) af[kk] = *(const bf16x8*)(crow + kk * 32 + quad * 8);
    __syncthreads();
    f32x4 zero = {0.f, 0.f, 0.f, 0.f};
    f32x4 acc[4] = {zero, zero, zero, zero};
#pragma unroll
    for (int kk = 0; kk < 8; ++kk) {
        int k0 = kk * 32 + quad * 8;
#pragma unroll
        for (int nb = 0; nb < 4; ++nb)
            acc[nb] = MFMA_K32(*(const bf16x8*)(&WS[nb * 16 + c16][k0]),
                               af[kk], acc[nb]);  // D[o][token]
    }
    int bb = M0 >> 12, n = (M0 + c16) & 4095;
#pragma unroll
    for (int nb = 0; nb < 4; ++nb)
#pragma unroll
        for (int r = 0; r < 4; ++r) {
            int o = O0 + nb * 16 + quad * 4 + r;
            out[((size_t)(bb * 256 + o) << 12) + n] = acc[nb][r] + bo[o];
        }
}

extern "C" void kernel_launch(void* const* d_in, const int* in_sizes, int n_in,
                              void* d_out, int out_size, void* d_ws, size_t ws_size,
                              hipStream_t stream) {
    const float* x  = (const float*)d_in[0];
    const float* Wq = (const float*)d_in[1];
    const float* bq = (const float*)d_in[2];
    const float* Wk = (const float*)d_in[3];
    const float* bk = (const float*)d_in[4];
    const float* Wv = (const float*)d_in[5];
    const float* bv = (const float*)d_in[6];
    const float* Wo = (const float*)d_in[7];
    const float* bo = (const float*)d_in[8];
    float* out = (float*)d_out;

    uint16_t* ws   = (uint16_t*)d_ws;
    uint16_t* Wb   = ws;                  // 4*65536 bf16
    uint16_t* tok  = Wb + 4 * 65536;      // [b,N,c]
    uint16_t* q    = tok + 2097152;       // [bh,n,d]
    uint16_t* k    = q + 2097152;         // [bh,n,d]
    uint16_t* vt   = k + 2097152;         // [bh,d,n]
    uint16_t* cc   = vt + 2097152;        // [b,n,c]

    prep<<<1024, 512, 0, stream>>>(x, Wq, Wk, Wv, Wo, Wb, tok);
    qkv_gemm<<<dim3(128, 4), 256, 0, stream>>>(tok, Wb, bq, bk, bv, q, k, vt);
    flash<<<dim3(32, 16), 512, 0, stream>>>(q, k, vt, cc);
    proj_gemm<<<dim3(128, 4), 256, 0, stream>>>(cc, Wb + 3 * 65536, bo, out);
}